// Round 8
// baseline (115.703 us; speedup 1.0000x reference)
//
#include <hip/hip_runtime.h>

// Problem constants (from reference setup_inputs): B=32, T=1000, I=256, H=512
#define BATCH 32
#define TSTEPS 1000
#define KDIM 256
#define HDIM 512
#define NSEG 8    // T-segments for the parallel scan
#define SEGL 125  // TSTEPS / NSEG
#define SPFD 25   // prefetch depth; SEGL % SPFD == 0 (REQUIRED: unrolled tail)

#define ALPHA_MIN_F 0.8187307530779818f
#define ALPHA_MAX_F 0.9607894391523232f

typedef __attribute__((ext_vector_type(8))) short bf16x8;          // 8 bf16
typedef __attribute__((ext_vector_type(8))) unsigned short u16x8;  // 16B store
typedef __attribute__((ext_vector_type(4))) float f32x4;

static __device__ __forceinline__ unsigned short f2bf(float f) {
  unsigned u = __float_as_uint(f);
  u += 0x7FFF + ((u >> 16) & 1);  // round-to-nearest-even
  return (unsigned short)(u >> 16);
}
static __device__ __forceinline__ float bf2f(unsigned short s) {
  return __uint_as_float(((unsigned)s) << 16);
}

__global__ void init_fs(int* fs) {
  if (threadIdx.x < BATCH) fs[threadIdx.x] = TSTEPS;
}

// ---------------------------------------------------------------------------
// Split-cast + fragment pack (round-5-proven; used for W only):
// packed[((tile*8+ks)*64+lane)*8+e] = src[tile*16+(lane&15)][(lane>>4)*8+ks*32+e]
// ---------------------------------------------------------------------------
__global__ __launch_bounds__(256) void cast_pack(const float* __restrict__ src,
                                                 unsigned short* __restrict__ hi,
                                                 unsigned short* __restrict__ lo,
                                                 int ntiles) {
  const int tile = blockIdx.x * 4 + (threadIdx.x >> 6);
  if (tile >= ntiles) return;
  const int lane = threadIdx.x & 63;
  const int row = tile * 16 + (lane & 15);
  const int kg = lane >> 4;
  const float* sp = src + (size_t)row * KDIM + kg * 8;
  unsigned short* hp = hi + (size_t)tile * 8 * 512 + lane * 8;
  unsigned short* lp = lo + (size_t)tile * 8 * 512 + lane * 8;
#pragma unroll
  for (int ks = 0; ks < 8; ++ks) {
    float4 a = *reinterpret_cast<const float4*>(sp + ks * 32);
    float4 b = *reinterpret_cast<const float4*>(sp + ks * 32 + 4);
    u16x8 h, l;
    h[0] = f2bf(a.x); l[0] = f2bf(a.x - bf2f(h[0]));
    h[1] = f2bf(a.y); l[1] = f2bf(a.y - bf2f(h[1]));
    h[2] = f2bf(a.z); l[2] = f2bf(a.z - bf2f(h[2]));
    h[3] = f2bf(a.w); l[3] = f2bf(a.w - bf2f(h[3]));
    h[4] = f2bf(b.x); l[4] = f2bf(b.x - bf2f(h[4]));
    h[5] = f2bf(b.y); l[5] = f2bf(b.y - bf2f(h[5]));
    h[6] = f2bf(b.z); l[6] = f2bf(b.z - bf2f(h[6]));
    h[7] = f2bf(b.w); l[7] = f2bf(b.w - bf2f(h[7]));
    *reinterpret_cast<u16x8*>(hp + ks * 512) = h;
    *reinterpret_cast<u16x8*>(lp + ks * 512) = l;
  }
}

// ---------------------------------------------------------------------------
// MFMA GEMM round-8: barrier-free main phase.
//   - Block = 8 waves (512 thr), grid (125, 4). blockIdx.y = n-quarter.
//   - Stage the WHOLE W n-quarter (8 n-tiles x 8 ks, hi+lo, fragment-packed,
//     128 KB) into LDS ONCE; single __syncthreads(); then each wave runs its
//     one 32-row m-pair against all 8 n-tiles with NO further barriers
//     (round-6/7's 42us came from 32 per-ct barrier+vmcnt drains).
//   - A (f32 x) loads are issued BEFORE staging so HBM latency hides under
//     the staging+barrier; split to hi/lo bf16 in-registers after.
//   - Numerics bitwise-identical to round-7: same fragment map, same 3
//     accumulator chains (hh, lh, hl) over ks ascending, same (A+B)+C.
// C/D mapping (m89-verified): col=lane&15, row=4*(lane>>4)+reg.
// ---------------------------------------------------------------------------
__global__ __launch_bounds__(512, 2) void gemm_mfma2(
    const float* __restrict__ x, const unsigned short* __restrict__ wph,
    const unsigned short* __restrict__ wpl, float* __restrict__ wx) {
  __shared__ unsigned short wlds[2][32768];  // [hi/lo][(tl*8+ks)*512+lane*8], 128 KB
  const int tid = threadIdx.x;
  const int lane = tid & 63;
  const int wid = tid >> 6;  // 0..7
  const int row = lane & 15;
  const int kg = lane >> 4;
  const int nq = blockIdx.y;                // n-quarter: cols [nq*128, +128)
  const int p = blockIdx.x * 8 + wid;       // m-pair id 0..999
  const int m0 = p * 32;

  // Issue A loads early (32 independent 16B loads; complete during staging).
  f32x4 araw[2][16];
#pragma unroll
  for (int mt = 0; mt < 2; ++mt) {
    const float* xp = x + (size_t)(m0 + mt * 16 + row) * KDIM + kg * 8;
#pragma unroll
    for (int ks = 0; ks < 8; ++ks) {
      araw[mt][ks * 2 + 0] = *reinterpret_cast<const f32x4*>(xp + ks * 32);
      araw[mt][ks * 2 + 1] = *reinterpret_cast<const f32x4*>(xp + ks * 32 + 4);
    }
  }

  // Stage W quarter: hi+lo, 65536 shorts each; 512 threads x 8 x 16B per half.
  {
    const unsigned short* sh = wph + (size_t)nq * 32768;
    const unsigned short* sl = wpl + (size_t)nq * 32768;
#pragma unroll
    for (int r = 0; r < 8; ++r) {
      const int o = (r * 512 + tid) * 8;
      *reinterpret_cast<bf16x8*>(&wlds[0][o]) =
          *reinterpret_cast<const bf16x8*>(sh + o);
      *reinterpret_cast<bf16x8*>(&wlds[1][o]) =
          *reinterpret_cast<const bf16x8*>(sl + o);
    }
  }
  __syncthreads();

  // Split A to hi/lo bf16 fragments (round-7 math, bitwise-identical).
  bf16x8 ah[2][8], al[2][8];
#pragma unroll
  for (int mt = 0; mt < 2; ++mt) {
#pragma unroll
    for (int ks = 0; ks < 8; ++ks) {
      f32x4 f0 = araw[mt][ks * 2 + 0];
      f32x4 f1 = araw[mt][ks * 2 + 1];
      bf16x8 hv, lv;
      hv[0] = (short)f2bf(f0[0]); lv[0] = (short)f2bf(f0[0] - bf2f(hv[0]));
      hv[1] = (short)f2bf(f0[1]); lv[1] = (short)f2bf(f0[1] - bf2f(hv[1]));
      hv[2] = (short)f2bf(f0[2]); lv[2] = (short)f2bf(f0[2] - bf2f(hv[2]));
      hv[3] = (short)f2bf(f0[3]); lv[3] = (short)f2bf(f0[3] - bf2f(hv[3]));
      hv[4] = (short)f2bf(f1[0]); lv[4] = (short)f2bf(f1[0] - bf2f(hv[4]));
      hv[5] = (short)f2bf(f1[1]); lv[5] = (short)f2bf(f1[1] - bf2f(hv[5]));
      hv[6] = (short)f2bf(f1[2]); lv[6] = (short)f2bf(f1[2] - bf2f(hv[6]));
      hv[7] = (short)f2bf(f1[3]); lv[7] = (short)f2bf(f1[3] - bf2f(hv[7]));
      ah[mt][ks] = hv;
      al[mt][ks] = lv;
    }
  }

  // Barrier-free MFMA phase: 8 local n-tiles x (2 m-tiles x 3 chains x 8 ks).
#pragma unroll
  for (int tl = 0; tl < 8; ++tl) {
    f32x4 accA[2] = {{0.f, 0.f, 0.f, 0.f}, {0.f, 0.f, 0.f, 0.f}};  // hh
    f32x4 accB[2] = {{0.f, 0.f, 0.f, 0.f}, {0.f, 0.f, 0.f, 0.f}};  // lh
    f32x4 accC[2] = {{0.f, 0.f, 0.f, 0.f}, {0.f, 0.f, 0.f, 0.f}};  // hl
#pragma unroll
    for (int ks = 0; ks < 8; ++ks) {
      const int o = (tl * 8 + ks) * 512 + lane * 8;
      bf16x8 bh = *reinterpret_cast<const bf16x8*>(&wlds[0][o]);
      bf16x8 bl = *reinterpret_cast<const bf16x8*>(&wlds[1][o]);
#pragma unroll
      for (int mt = 0; mt < 2; ++mt) {
        accA[mt] = __builtin_amdgcn_mfma_f32_16x16x32_bf16(ah[mt][ks], bh, accA[mt], 0, 0, 0);
        accB[mt] = __builtin_amdgcn_mfma_f32_16x16x32_bf16(al[mt][ks], bh, accB[mt], 0, 0, 0);
        accC[mt] = __builtin_amdgcn_mfma_f32_16x16x32_bf16(ah[mt][ks], bl, accC[mt], 0, 0, 0);
      }
    }
    const int n0 = nq * 128 + tl * 16;
#pragma unroll
    for (int mt = 0; mt < 2; ++mt) {
#pragma unroll
      for (int j = 0; j < 4; ++j) {
        wx[(size_t)(m0 + mt * 16 + kg * 4 + j) * HDIM + n0 + row] =
            (accA[mt][j] + accB[mt][j]) + accC[mt][j];
      }
    }
  }
}

// ---------------------------------------------------------------------------
// Pass A: per-(b,seg,h) particular solution of the LINEAR recurrence over the
// segment: c = sum_j a^(SEGL-1-j) * na * w_j, computed by the same iteration
// c = fma(a, c, na*w). 2048 waves -> BW-bound.
// ---------------------------------------------------------------------------
__global__ __launch_bounds__(64) void seg_sum(const float* __restrict__ wx,
                                              const float* __restrict__ alpha,
                                              float* __restrict__ cbuf) {
  const int hb = blockIdx.x & 7;
  const int seg = (blockIdx.x >> 3) & 7;
  const int b = blockIdx.x >> 6;
  const int h = (hb << 6) + threadIdx.x;
  const float a = fminf(fmaxf(alpha[h], ALPHA_MIN_F), ALPHA_MAX_F);
  const float na = 1.0f - a;
  const float* wp = wx + ((size_t)b * TSTEPS + seg * SEGL) * HDIM + h;

  float pf[SPFD];
#pragma unroll
  for (int d = 0; d < SPFD; ++d) pf[d] = wp[(size_t)d * HDIM];

  float c = 0.f;
  for (int j0 = 0; j0 < SEGL; j0 += SPFD) {
#pragma unroll
    for (int js = 0; js < SPFD; ++js) {
      const int j = j0 + js;
      const float w = pf[js];
      int jp = j + SPFD;
      if (jp > SEGL - 1) jp = SEGL - 1;  // clamped in-segment tail reload
      pf[js] = wp[(size_t)jp * HDIM];
      c = fmaf(a, c, na * w);
    }
  }
  cbuf[(size_t)seg * BATCH * HDIM + (size_t)b * HDIM + h] = c;
}

// ---------------------------------------------------------------------------
// Pass B: reconstruct the linear boundary state u_start = fold_k fma(a^SEGL,
// u, c_k), then run the NONLINEAR per-channel dynamics (self-reset, r=0) for
// the segment. Exact (to ulp) up to the batch's first true spike t*: before
// t* the true dynamics are linear, so every segment start below/at t* is
// right, t* is detected exactly via atomicMin, and spurious later spikes
// cannot lower the min. Spiking batches are rewritten by fallback_scan.
// ---------------------------------------------------------------------------
__global__ __launch_bounds__(64) void seg_scan(const float* __restrict__ wx,
                                               const float* __restrict__ alpha,
                                               const float* __restrict__ vthr,
                                               const float* __restrict__ cbuf,
                                               float* __restrict__ out,
                                               int* __restrict__ fs) {
  const int hb = blockIdx.x & 7;
  const int seg = (blockIdx.x >> 3) & 7;
  const int b = blockIdx.x >> 6;
  const int h = (hb << 6) + threadIdx.x;
  const float a = fminf(fmaxf(alpha[h], ALPHA_MIN_F), ALPHA_MAX_F);
  const float na = 1.0f - a;
  const float th = vthr[h];
  const int t0g = seg * SEGL;
  const float* wp = wx + ((size_t)b * TSTEPS + t0g) * HDIM + h;
  float* op = out + ((size_t)b * TSTEPS + t0g) * HDIM + h;

  // Issue the prefetch pipeline first so it overlaps the u_start computation.
  float pf[SPFD];
#pragma unroll
  for (int d = 0; d < SPFD; ++d) pf[d] = wp[(size_t)d * HDIM];

  // a^SEGL (serial mults; ~ulp-accurate on a tiny factor, error << threshold)
  float aL = 1.0f;
  for (int i = 0; i < SEGL; ++i) aL *= a;
  float u = 0.f;
  for (int k = 0; k < seg; ++k)  // wave-uniform bound (seg is block-wide)
    u = fmaf(aL, u, cbuf[(size_t)k * BATCH * HDIM + (size_t)b * HDIM + h]);

  float s = 0.f;
  int first = TSTEPS;
  for (int j0 = 0; j0 < SEGL; j0 += SPFD) {
#pragma unroll
    for (int js = 0; js < SPFD; ++js) {
      const int j = j0 + js;
      const float w = pf[js];
      int jp = j + SPFD;
      if (jp > SEGL - 1) jp = SEGL - 1;  // clamped in-segment tail reload
      pf[js] = wp[(size_t)jp * HDIM];
      u = fmaf(a, u - s, na * w);
      s = (u > th) ? 1.0f : 0.0f;
      op[(size_t)j * HDIM] = s;
      if (s != 0.0f && first == TSTEPS) {
        first = t0g + j;
        atomicMin(&fs[b], first);
      }
    }
  }
}

// ---------------------------------------------------------------------------
// Full coupled scan body (round-1-proven): one wave per batch, sparse s@Vz
// via ballot. Used gated (fallback) and ungated (tiny-ws tier).
// ---------------------------------------------------------------------------
static __device__ __forceinline__ void scan_body(const float* wxbuf,
                                                 const float* __restrict__ V,
                                                 const float* __restrict__ alpha,
                                                 const float* __restrict__ vthr,
                                                 float* out, int b) {
  const int l = threadIdx.x;
  const int h0 = 4 * l;
  const int h1 = 256 + 4 * l;

  float4 al0 = *reinterpret_cast<const float4*>(alpha + h0);
  float4 al1 = *reinterpret_cast<const float4*>(alpha + h1);
  float4 th0 = *reinterpret_cast<const float4*>(vthr + h0);
  float4 th1 = *reinterpret_cast<const float4*>(vthr + h1);
  float a[8] = {al0.x, al0.y, al0.z, al0.w, al1.x, al1.y, al1.z, al1.w};
  float th[8] = {th0.x, th0.y, th0.z, th0.w, th1.x, th1.y, th1.z, th1.w};
  float na[8], u[8], s[8], r[8];
#pragma unroll
  for (int j = 0; j < 8; ++j) {
    float c = fminf(fmaxf(a[j], ALPHA_MIN_F), ALPHA_MAX_F);
    a[j] = c; na[j] = 1.0f - c;
    u[j] = 0.f; s[j] = 0.f; r[j] = 0.f;
  }
  const float* wb = wxbuf + (size_t)b * TSTEPS * HDIM;
  float* ob = out + (size_t)b * TSTEPS * HDIM;
  float4 p0[4], p1[4];
#pragma unroll
  for (int d = 0; d < 4; ++d) {
    p0[d] = *reinterpret_cast<const float4*>(wb + (size_t)d * HDIM + h0);
    p1[d] = *reinterpret_cast<const float4*>(wb + (size_t)d * HDIM + h1);
  }
  for (int t0 = 0; t0 < TSTEPS; t0 += 4) {
#pragma unroll
    for (int ts = 0; ts < 4; ++ts) {
      const int t = t0 + ts;
      float w8[8] = {p0[ts].x, p0[ts].y, p0[ts].z, p0[ts].w,
                     p1[ts].x, p1[ts].y, p1[ts].z, p1[ts].w};
      int tpre = t + 4;
      if (tpre > TSTEPS - 1) tpre = TSTEPS - 1;
      p0[ts] = *reinterpret_cast<const float4*>(wb + (size_t)tpre * HDIM + h0);
      p1[ts] = *reinterpret_cast<const float4*>(wb + (size_t)tpre * HDIM + h1);
#pragma unroll
      for (int j = 0; j < 8; ++j) {
        float un = fmaf(a[j], u[j] - s[j], na[j] * (w8[j] + r[j]));
        u[j] = un;
        s[j] = (un > th[j]) ? 1.0f : 0.0f;
      }
      *reinterpret_cast<float4*>(ob + (size_t)t * HDIM + h0) =
          make_float4(s[0], s[1], s[2], s[3]);
      *reinterpret_cast<float4*>(ob + (size_t)t * HDIM + h1) =
          make_float4(s[4], s[5], s[6], s[7]);
      float ssum = s[0] + s[1] + s[2] + s[3] + s[4] + s[5] + s[6] + s[7];
      unsigned long long anym = __ballot(ssum != 0.0f);
      if (anym != 0ull) {
        unsigned long long mk[8];
#pragma unroll
        for (int j = 0; j < 8; ++j) mk[j] = __ballot(s[j] != 0.0f);
        float rr[8] = {0.f, 0.f, 0.f, 0.f, 0.f, 0.f, 0.f, 0.f};
#pragma unroll
        for (int j2 = 0; j2 < 8; ++j2) {
          unsigned long long m = mk[j2];
          while (m) {  // wave-uniform (masks identical on all lanes)
            int src = __builtin_ctzll(m);
            m &= m - 1;
            int hin = (j2 < 4) ? (src * 4 + j2) : (256 + src * 4 + (j2 - 4));
            const float* vrow = V + (size_t)hin * HDIM;
            float4 v0 = *reinterpret_cast<const float4*>(vrow + h0);
            float4 v1 = *reinterpret_cast<const float4*>(vrow + h1);
            float vv[8] = {v0.x, v0.y, v0.z, v0.w, v1.x, v1.y, v1.z, v1.w};
#pragma unroll
            for (int j = 0; j < 8; ++j) {
              int hj = (j < 4) ? (h0 + j) : (h1 + j - 4);
              rr[j] += (hj == hin) ? 0.0f : vv[j];  // zeroed diagonal
            }
          }
        }
#pragma unroll
        for (int j = 0; j < 8; ++j) r[j] = rr[j];
      } else {
#pragma unroll
        for (int j = 0; j < 8; ++j) r[j] = 0.0f;
      }
    }
  }
}

// Gated fallback: only batches whose first spike is at t <= TSTEPS-2 need the
// coupled recompute (a spike at the last step cannot affect any output).
__global__ __launch_bounds__(64) void fallback_scan(
    const float* wxbuf, const float* __restrict__ V,
    const float* __restrict__ alpha, const float* __restrict__ vthr,
    float* out, const int* __restrict__ fs) {
  const int b = blockIdx.x;
  if (fs[b] >= TSTEPS - 1) return;
  scan_body(wxbuf, V, alpha, vthr, out, b);
}

// Ungated (tiny-ws tier, round-1 semantics).
__global__ __launch_bounds__(64) void rlif_scan(const float* wxbuf,
                                                const float* __restrict__ V,
                                                const float* __restrict__ alpha,
                                                const float* __restrict__ vthr,
                                                float* out) {
  scan_body(wxbuf, V, alpha, vthr, out, blockIdx.x);
}

// ---------------------------------------------------------------------------
// Tier-B f32 GEMM (round-1-proven).
// ---------------------------------------------------------------------------
__global__ __launch_bounds__(256) void gemm_xwT(const float* __restrict__ x,
                                                const float* __restrict__ W,
                                                float* __restrict__ wx) {
  __shared__ float As[32][64];
  __shared__ float Bs[32][64];
  const int m0 = blockIdx.x * 64;
  const int n0 = blockIdx.y * 64;
  const int tid = threadIdx.x;
  const int tx = tid & 15;
  const int ty = tid >> 4;
  const int lr = tid >> 2;
  const int lk = (tid & 3) * 8;

  float acc[4][4] = {};
  for (int k0 = 0; k0 < KDIM; k0 += 32) {
    const float4* ap =
        reinterpret_cast<const float4*>(x + (size_t)(m0 + lr) * KDIM + k0 + lk);
    const float4* bp =
        reinterpret_cast<const float4*>(W + (size_t)(n0 + lr) * KDIM + k0 + lk);
    float4 a0 = ap[0], a1 = ap[1];
    float4 b0 = bp[0], b1 = bp[1];
    __syncthreads();
    As[lk + 0][lr] = a0.x; As[lk + 1][lr] = a0.y;
    As[lk + 2][lr] = a0.z; As[lk + 3][lr] = a0.w;
    As[lk + 4][lr] = a1.x; As[lk + 5][lr] = a1.y;
    As[lk + 6][lr] = a1.z; As[lk + 7][lr] = a1.w;
    Bs[lk + 0][lr] = b0.x; Bs[lk + 1][lr] = b0.y;
    Bs[lk + 2][lr] = b0.z; Bs[lk + 3][lr] = b0.w;
    Bs[lk + 4][lr] = b1.x; Bs[lk + 5][lr] = b1.y;
    Bs[lk + 6][lr] = b1.z; Bs[lk + 7][lr] = b1.w;
    __syncthreads();
#pragma unroll
    for (int k = 0; k < 32; ++k) {
      float4 av = *reinterpret_cast<const float4*>(&As[k][ty * 4]);
      float4 bv = *reinterpret_cast<const float4*>(&Bs[k][tx * 4]);
      float am[4] = {av.x, av.y, av.z, av.w};
      float bn[4] = {bv.x, bv.y, bv.z, bv.w};
#pragma unroll
      for (int i = 0; i < 4; ++i)
#pragma unroll
        for (int j = 0; j < 4; ++j) acc[i][j] = fmaf(am[i], bn[j], acc[i][j]);
    }
  }
#pragma unroll
  for (int i = 0; i < 4; ++i) {
    float4 o = make_float4(acc[i][0], acc[i][1], acc[i][2], acc[i][3]);
    *reinterpret_cast<float4*>(wx + (size_t)(m0 + ty * 4 + i) * HDIM + n0 +
                               tx * 4) = o;
  }
}

extern "C" void kernel_launch(void* const* d_in, const int* in_sizes, int n_in,
                              void* d_out, int out_size, void* d_ws,
                              size_t ws_size, hipStream_t stream) {
  const float* x = (const float*)d_in[0];      // [32,1000,256]
  const float* W = (const float*)d_in[1];      // [512,256]
  const float* V = (const float*)d_in[2];      // [512,512]
  const float* alpha = (const float*)d_in[3];  // [512]
  const float* vthr = (const float*)d_in[4];   // [512]
  float* out = (float*)d_out;                  // [32,1000,512]

  const size_t wx_b = (size_t)BATCH * TSTEPS * HDIM * 4;  // 65,536,000
  const size_t wh_b = (size_t)HDIM * KDIM * 2;            //    262,144 (each)
  const size_t cb_b = (size_t)NSEG * BATCH * HDIM * 4;    //    524,288
  const size_t needA = wx_b + 2 * wh_b + cb_b + 128;      // ~66.6 MB
  const size_t needB = wx_b + cb_b + 128;

  char* ws = (char*)d_ws;
  if (ws_size >= needA) {
    float* wx = (float*)ws;
    unsigned short* wph = (unsigned short*)(ws + wx_b);
    unsigned short* wpl = wph + (size_t)HDIM * KDIM;
    float* cbuf = (float*)(ws + wx_b + 2 * wh_b);
    int* fs = (int*)(ws + wx_b + 2 * wh_b + cb_b);

    hipLaunchKernelGGL(init_fs, dim3(1), dim3(64), 0, stream, fs);
    hipLaunchKernelGGL(cast_pack, dim3(8), dim3(256), 0, stream, W, wph, wpl,
                       HDIM / 16);
    // 1000 m-pairs x 4 n-quarters; 8 waves/block, 1 pair per wave.
    hipLaunchKernelGGL(gemm_mfma2, dim3(125, 4), dim3(512), 0, stream, x, wph,
                       wpl, wx);
    hipLaunchKernelGGL(seg_sum, dim3(BATCH * NSEG * 8), dim3(64), 0, stream,
                       wx, alpha, cbuf);
    hipLaunchKernelGGL(seg_scan, dim3(BATCH * NSEG * 8), dim3(64), 0, stream,
                       wx, alpha, vthr, cbuf, out, fs);
    hipLaunchKernelGGL(fallback_scan, dim3(BATCH), dim3(64), 0, stream, wx, V,
                       alpha, vthr, out, fs);
  } else if (ws_size >= needB) {
    float* wx = (float*)ws;
    float* cbuf = (float*)(ws + wx_b);
    int* fs = (int*)(ws + wx_b + cb_b);
    hipLaunchKernelGGL(init_fs, dim3(1), dim3(64), 0, stream, fs);
    hipLaunchKernelGGL(gemm_xwT, dim3(BATCH * TSTEPS / 64, HDIM / 64),
                       dim3(256), 0, stream, x, W, wx);
    hipLaunchKernelGGL(seg_sum, dim3(BATCH * NSEG * 8), dim3(64), 0, stream,
                       wx, alpha, cbuf);
    hipLaunchKernelGGL(seg_scan, dim3(BATCH * NSEG * 8), dim3(64), 0, stream,
                       wx, alpha, vthr, cbuf, out, fs);
    hipLaunchKernelGGL(fallback_scan, dim3(BATCH), dim3(64), 0, stream, wx, V,
                       alpha, vthr, out, fs);
  } else {
    float* wx = (ws_size >= wx_b) ? (float*)ws : out;
    hipLaunchKernelGGL(gemm_xwT, dim3(BATCH * TSTEPS / 64, HDIM / 64),
                       dim3(256), 0, stream, x, W, wx);
    hipLaunchKernelGGL(rlif_scan, dim3(BATCH), dim3(64), 0, stream, wx, V,
                       alpha, vthr, out);
  }
}

// Round 9
// 82.654 us; speedup vs baseline: 1.3998x; 1.3998x over previous
//
#include <hip/hip_runtime.h>

// Problem constants (from reference setup_inputs): B=32, T=1000, I=256, H=512
#define BATCH 32
#define TSTEPS 1000
#define KDIM 256
#define HDIM 512
#define NSEG 8    // T-segments for the parallel scan
#define SEGL 125  // TSTEPS / NSEG
#define SPFD 25   // prefetch depth; SEGL % SPFD == 0 (REQUIRED: unrolled tail)

#define ALPHA_MIN_F 0.8187307530779818f
#define ALPHA_MAX_F 0.9607894391523232f

typedef __attribute__((ext_vector_type(8))) short bf16x8;          // 8 bf16
typedef __attribute__((ext_vector_type(8))) unsigned short u16x8;  // 16B store
typedef __attribute__((ext_vector_type(4))) float f32x4;

static __device__ __forceinline__ unsigned short f2bf(float f) {
  unsigned u = __float_as_uint(f);
  u += 0x7FFF + ((u >> 16) & 1);  // round-to-nearest-even
  return (unsigned short)(u >> 16);
}
static __device__ __forceinline__ float bf2f(unsigned short s) {
  return __uint_as_float(((unsigned)s) << 16);
}

__global__ void init_fs(int* fs) {
  if (threadIdx.x < BATCH) fs[threadIdx.x] = TSTEPS;
}

// ---------------------------------------------------------------------------
// Split-cast + fragment pack (round-5-proven; used for W only):
// packed[((tile*8+ks)*64+lane)*8+e] = src[tile*16+(lane&15)][(lane>>4)*8+ks*32+e]
// ---------------------------------------------------------------------------
__global__ __launch_bounds__(256) void cast_pack(const float* __restrict__ src,
                                                 unsigned short* __restrict__ hi,
                                                 unsigned short* __restrict__ lo,
                                                 int ntiles) {
  const int tile = blockIdx.x * 4 + (threadIdx.x >> 6);
  if (tile >= ntiles) return;
  const int lane = threadIdx.x & 63;
  const int row = tile * 16 + (lane & 15);
  const int kg = lane >> 4;
  const float* sp = src + (size_t)row * KDIM + kg * 8;
  unsigned short* hp = hi + (size_t)tile * 8 * 512 + lane * 8;
  unsigned short* lp = lo + (size_t)tile * 8 * 512 + lane * 8;
#pragma unroll
  for (int ks = 0; ks < 8; ++ks) {
    float4 a = *reinterpret_cast<const float4*>(sp + ks * 32);
    float4 b = *reinterpret_cast<const float4*>(sp + ks * 32 + 4);
    u16x8 h, l;
    h[0] = f2bf(a.x); l[0] = f2bf(a.x - bf2f(h[0]));
    h[1] = f2bf(a.y); l[1] = f2bf(a.y - bf2f(h[1]));
    h[2] = f2bf(a.z); l[2] = f2bf(a.z - bf2f(h[2]));
    h[3] = f2bf(a.w); l[3] = f2bf(a.w - bf2f(h[3]));
    h[4] = f2bf(b.x); l[4] = f2bf(b.x - bf2f(h[4]));
    h[5] = f2bf(b.y); l[5] = f2bf(b.y - bf2f(h[5]));
    h[6] = f2bf(b.z); l[6] = f2bf(b.z - bf2f(h[6]));
    h[7] = f2bf(b.w); l[7] = f2bf(b.w - bf2f(h[7]));
    *reinterpret_cast<u16x8*>(hp + ks * 512) = h;
    *reinterpret_cast<u16x8*>(lp + ks * 512) = l;
  }
}

// ---------------------------------------------------------------------------
// MFMA GEMM round-9: round-7's PROVEN kernel (42us, 96 VGPR, no spills) with
// ONE change: block = 2 waves (128 thr) instead of 4 -> grid 1000 blocks ->
// ~4 resident blocks/CU (was 1.95, grid-limited). Independent per-block
// barriers overlap: while one block drains vmcnt at its barrier, the other
// blocks' MFMA phases keep the SIMDs fed. Math/staging/fragment layout
// byte-identical to round-7 (which passed with absmax 0).
//   A: direct from f32 x, split hi/lo in-registers (k-map (lane>>4)*8+ks*32+e)
//   B: packed W staged per n-tile into 32KB LDS (double-buffered,
//      issue-early / write-late), 3 accumulator chains (hh, lh, hl).
// C/D mapping (m89-verified): col=lane&15, row=4*(lane>>4)+reg.
// ---------------------------------------------------------------------------
__global__ __launch_bounds__(128, 2) void gemm_mfma3(
    const float* __restrict__ x, const unsigned short* __restrict__ wph,
    const unsigned short* __restrict__ wpl, float* __restrict__ wx) {
  __shared__ short bsh[2][2][4096];  // [buf][hi/lo][ks*512 + lane*8 + e], 32KB
  const int tid = threadIdx.x;       // 0..127
  const int lane = tid & 63;
  const int wid = tid >> 6;          // 0..1
  const int row = lane & 15;
  const int kg = lane >> 4;
  const int tm = blockIdx.x * 2 + wid;  // this wave's single m-tile (0..1999)
  const int m0 = tm * 16;

  // A fragments: 8 ks, hi & lo, split from f32 in-registers (round-7 code).
  bf16x8 ah[8], al[8];
  const float* xp = x + (size_t)(m0 + row) * KDIM + kg * 8;
#pragma unroll
  for (int ks = 0; ks < 8; ++ks) {
    float4 f0 = *reinterpret_cast<const float4*>(xp + ks * 32);
    float4 f1 = *reinterpret_cast<const float4*>(xp + ks * 32 + 4);
    bf16x8 hv, lv;
    hv[0] = (short)f2bf(f0.x); lv[0] = (short)f2bf(f0.x - bf2f(hv[0]));
    hv[1] = (short)f2bf(f0.y); lv[1] = (short)f2bf(f0.y - bf2f(hv[1]));
    hv[2] = (short)f2bf(f0.z); lv[2] = (short)f2bf(f0.z - bf2f(hv[2]));
    hv[3] = (short)f2bf(f0.w); lv[3] = (short)f2bf(f0.w - bf2f(hv[3]));
    hv[4] = (short)f2bf(f1.x); lv[4] = (short)f2bf(f1.x - bf2f(hv[4]));
    hv[5] = (short)f2bf(f1.y); lv[5] = (short)f2bf(f1.y - bf2f(hv[5]));
    hv[6] = (short)f2bf(f1.z); lv[6] = (short)f2bf(f1.z - bf2f(hv[6]));
    hv[7] = (short)f2bf(f1.w); lv[7] = (short)f2bf(f1.w - bf2f(hv[7]));
    ah[ks] = hv;
    al[ks] = lv;
  }

  // Prologue: stage n-tile 0 into buf 0 (128 threads x 4 x 16B per half).
#pragma unroll
  for (int r = 0; r < 4; ++r) {
    const int o = r * 1024 + tid * 8;
    *reinterpret_cast<bf16x8*>(&bsh[0][0][o]) =
        *reinterpret_cast<const bf16x8*>(wph + o);
    *reinterpret_cast<bf16x8*>(&bsh[0][1][o]) =
        *reinterpret_cast<const bf16x8*>(wpl + o);
  }
  __syncthreads();

  for (int ct = 0; ct < 32; ++ct) {
    const int buf = ct & 1;
    // Issue next tile's global loads early (latency hidden under MFMAs).
    bf16x8 nh[4], nl[4];
    const bool pre = (ct < 31);
    if (pre) {
      const unsigned short* sh = wph + (size_t)(ct + 1) * 4096;
      const unsigned short* sl = wpl + (size_t)(ct + 1) * 4096;
#pragma unroll
      for (int r = 0; r < 4; ++r) {
        const int o = r * 1024 + tid * 8;
        nh[r] = *reinterpret_cast<const bf16x8*>(sh + o);
        nl[r] = *reinterpret_cast<const bf16x8*>(sl + o);
      }
    }

    f32x4 accA = {0.f, 0.f, 0.f, 0.f};  // hh
    f32x4 accB = {0.f, 0.f, 0.f, 0.f};  // lh
    f32x4 accC = {0.f, 0.f, 0.f, 0.f};  // hl
#pragma unroll
    for (int ks = 0; ks < 8; ++ks) {
      bf16x8 bh = *reinterpret_cast<const bf16x8*>(&bsh[buf][0][ks * 512 + lane * 8]);
      bf16x8 bl = *reinterpret_cast<const bf16x8*>(&bsh[buf][1][ks * 512 + lane * 8]);
      accA = __builtin_amdgcn_mfma_f32_16x16x32_bf16(ah[ks], bh, accA, 0, 0, 0);
      accB = __builtin_amdgcn_mfma_f32_16x16x32_bf16(al[ks], bh, accB, 0, 0, 0);
      accC = __builtin_amdgcn_mfma_f32_16x16x32_bf16(ah[ks], bl, accC, 0, 0, 0);
    }
    const int n0 = ct * 16;
#pragma unroll
    for (int j = 0; j < 4; ++j) {
      wx[(size_t)(m0 + kg * 4 + j) * HDIM + n0 + row] =
          (accA[j] + accB[j]) + accC[j];
    }
    if (pre) {  // write-late into the other buffer
#pragma unroll
      for (int r = 0; r < 4; ++r) {
        const int o = r * 1024 + tid * 8;
        *reinterpret_cast<bf16x8*>(&bsh[buf ^ 1][0][o]) = nh[r];
        *reinterpret_cast<bf16x8*>(&bsh[buf ^ 1][1][o]) = nl[r];
      }
    }
    __syncthreads();
  }
}

// ---------------------------------------------------------------------------
// Pass A: per-(b,seg,h) particular solution of the LINEAR recurrence over the
// segment: c = sum_j a^(SEGL-1-j) * na * w_j, computed by the same iteration
// c = fma(a, c, na*w). Only segments 0..6 are ever consumed by seg_scan
// (k < seg <= 7), so segment 7 is skipped: grid = BATCH * 7 * 8.
// ---------------------------------------------------------------------------
__global__ __launch_bounds__(64) void seg_sum(const float* __restrict__ wx,
                                              const float* __restrict__ alpha,
                                              float* __restrict__ cbuf) {
  const int hb = blockIdx.x & 7;
  const int rest = blockIdx.x >> 3;  // 0..223
  const int seg = rest % 7;
  const int b = rest / 7;
  const int h = (hb << 6) + threadIdx.x;
  const float a = fminf(fmaxf(alpha[h], ALPHA_MIN_F), ALPHA_MAX_F);
  const float na = 1.0f - a;
  const float* wp = wx + ((size_t)b * TSTEPS + seg * SEGL) * HDIM + h;

  float pf[SPFD];
#pragma unroll
  for (int d = 0; d < SPFD; ++d) pf[d] = wp[(size_t)d * HDIM];

  float c = 0.f;
  for (int j0 = 0; j0 < SEGL; j0 += SPFD) {
#pragma unroll
    for (int js = 0; js < SPFD; ++js) {
      const int j = j0 + js;
      const float w = pf[js];
      int jp = j + SPFD;
      if (jp > SEGL - 1) jp = SEGL - 1;  // clamped in-segment tail reload
      pf[js] = wp[(size_t)jp * HDIM];
      c = fmaf(a, c, na * w);
    }
  }
  cbuf[(size_t)seg * BATCH * HDIM + (size_t)b * HDIM + h] = c;
}

// ---------------------------------------------------------------------------
// Pass B: reconstruct the linear boundary state u_start = fold_k fma(a^SEGL,
// u, c_k), then run the NONLINEAR per-channel dynamics (self-reset, r=0) for
// the segment. Exact (to ulp) up to the batch's first true spike t*: before
// t* the true dynamics are linear, so every segment start below/at t* is
// right, t* is detected exactly via atomicMin, and spurious later spikes
// cannot lower the min. Spiking batches are rewritten by fallback_scan.
// ---------------------------------------------------------------------------
__global__ __launch_bounds__(64) void seg_scan(const float* __restrict__ wx,
                                               const float* __restrict__ alpha,
                                               const float* __restrict__ vthr,
                                               const float* __restrict__ cbuf,
                                               float* __restrict__ out,
                                               int* __restrict__ fs) {
  const int hb = blockIdx.x & 7;
  const int seg = (blockIdx.x >> 3) & 7;
  const int b = blockIdx.x >> 6;
  const int h = (hb << 6) + threadIdx.x;
  const float a = fminf(fmaxf(alpha[h], ALPHA_MIN_F), ALPHA_MAX_F);
  const float na = 1.0f - a;
  const float th = vthr[h];
  const int t0g = seg * SEGL;
  const float* wp = wx + ((size_t)b * TSTEPS + t0g) * HDIM + h;
  float* op = out + ((size_t)b * TSTEPS + t0g) * HDIM + h;

  // Issue the prefetch pipeline first so it overlaps the u_start computation.
  float pf[SPFD];
#pragma unroll
  for (int d = 0; d < SPFD; ++d) pf[d] = wp[(size_t)d * HDIM];

  // a^SEGL (serial mults; ~ulp-accurate on a tiny factor, error << threshold)
  float aL = 1.0f;
  for (int i = 0; i < SEGL; ++i) aL *= a;
  float u = 0.f;
  for (int k = 0; k < seg; ++k)  // wave-uniform bound (seg is block-wide)
    u = fmaf(aL, u, cbuf[(size_t)k * BATCH * HDIM + (size_t)b * HDIM + h]);

  float s = 0.f;
  int first = TSTEPS;
  for (int j0 = 0; j0 < SEGL; j0 += SPFD) {
#pragma unroll
    for (int js = 0; js < SPFD; ++js) {
      const int j = j0 + js;
      const float w = pf[js];
      int jp = j + SPFD;
      if (jp > SEGL - 1) jp = SEGL - 1;  // clamped in-segment tail reload
      pf[js] = wp[(size_t)jp * HDIM];
      u = fmaf(a, u - s, na * w);
      s = (u > th) ? 1.0f : 0.0f;
      op[(size_t)j * HDIM] = s;
      if (s != 0.0f && first == TSTEPS) {
        first = t0g + j;
        atomicMin(&fs[b], first);
      }
    }
  }
}

// ---------------------------------------------------------------------------
// Full coupled scan body (round-1-proven): one wave per batch, sparse s@Vz
// via ballot. Used gated (fallback) and ungated (tiny-ws tier).
// ---------------------------------------------------------------------------
static __device__ __forceinline__ void scan_body(const float* wxbuf,
                                                 const float* __restrict__ V,
                                                 const float* __restrict__ alpha,
                                                 const float* __restrict__ vthr,
                                                 float* out, int b) {
  const int l = threadIdx.x;
  const int h0 = 4 * l;
  const int h1 = 256 + 4 * l;

  float4 al0 = *reinterpret_cast<const float4*>(alpha + h0);
  float4 al1 = *reinterpret_cast<const float4*>(alpha + h1);
  float4 th0 = *reinterpret_cast<const float4*>(vthr + h0);
  float4 th1 = *reinterpret_cast<const float4*>(vthr + h1);
  float a[8] = {al0.x, al0.y, al0.z, al0.w, al1.x, al1.y, al1.z, al1.w};
  float th[8] = {th0.x, th0.y, th0.z, th0.w, th1.x, th1.y, th1.z, th1.w};
  float na[8], u[8], s[8], r[8];
#pragma unroll
  for (int j = 0; j < 8; ++j) {
    float c = fminf(fmaxf(a[j], ALPHA_MIN_F), ALPHA_MAX_F);
    a[j] = c; na[j] = 1.0f - c;
    u[j] = 0.f; s[j] = 0.f; r[j] = 0.f;
  }
  const float* wb = wxbuf + (size_t)b * TSTEPS * HDIM;
  float* ob = out + (size_t)b * TSTEPS * HDIM;
  float4 p0[4], p1[4];
#pragma unroll
  for (int d = 0; d < 4; ++d) {
    p0[d] = *reinterpret_cast<const float4*>(wb + (size_t)d * HDIM + h0);
    p1[d] = *reinterpret_cast<const float4*>(wb + (size_t)d * HDIM + h1);
  }
  for (int t0 = 0; t0 < TSTEPS; t0 += 4) {
#pragma unroll
    for (int ts = 0; ts < 4; ++ts) {
      const int t = t0 + ts;
      float w8[8] = {p0[ts].x, p0[ts].y, p0[ts].z, p0[ts].w,
                     p1[ts].x, p1[ts].y, p1[ts].z, p1[ts].w};
      int tpre = t + 4;
      if (tpre > TSTEPS - 1) tpre = TSTEPS - 1;
      p0[ts] = *reinterpret_cast<const float4*>(wb + (size_t)tpre * HDIM + h0);
      p1[ts] = *reinterpret_cast<const float4*>(wb + (size_t)tpre * HDIM + h1);
#pragma unroll
      for (int j = 0; j < 8; ++j) {
        float un = fmaf(a[j], u[j] - s[j], na[j] * (w8[j] + r[j]));
        u[j] = un;
        s[j] = (un > th[j]) ? 1.0f : 0.0f;
      }
      *reinterpret_cast<float4*>(ob + (size_t)t * HDIM + h0) =
          make_float4(s[0], s[1], s[2], s[3]);
      *reinterpret_cast<float4*>(ob + (size_t)t * HDIM + h1) =
          make_float4(s[4], s[5], s[6], s[7]);
      float ssum = s[0] + s[1] + s[2] + s[3] + s[4] + s[5] + s[6] + s[7];
      unsigned long long anym = __ballot(ssum != 0.0f);
      if (anym != 0ull) {
        unsigned long long mk[8];
#pragma unroll
        for (int j = 0; j < 8; ++j) mk[j] = __ballot(s[j] != 0.0f);
        float rr[8] = {0.f, 0.f, 0.f, 0.f, 0.f, 0.f, 0.f, 0.f};
#pragma unroll
        for (int j2 = 0; j2 < 8; ++j2) {
          unsigned long long m = mk[j2];
          while (m) {  // wave-uniform (masks identical on all lanes)
            int src = __builtin_ctzll(m);
            m &= m - 1;
            int hin = (j2 < 4) ? (src * 4 + j2) : (256 + src * 4 + (j2 - 4));
            const float* vrow = V + (size_t)hin * HDIM;
            float4 v0 = *reinterpret_cast<const float4*>(vrow + h0);
            float4 v1 = *reinterpret_cast<const float4*>(vrow + h1);
            float vv[8] = {v0.x, v0.y, v0.z, v0.w, v1.x, v1.y, v1.z, v1.w};
#pragma unroll
            for (int j = 0; j < 8; ++j) {
              int hj = (j < 4) ? (h0 + j) : (h1 + j - 4);
              rr[j] += (hj == hin) ? 0.0f : vv[j];  // zeroed diagonal
            }
          }
        }
#pragma unroll
        for (int j = 0; j < 8; ++j) r[j] = rr[j];
      } else {
#pragma unroll
        for (int j = 0; j < 8; ++j) r[j] = 0.0f;
      }
    }
  }
}

// Gated fallback: only batches whose first spike is at t <= TSTEPS-2 need the
// coupled recompute (a spike at the last step cannot affect any output).
__global__ __launch_bounds__(64) void fallback_scan(
    const float* wxbuf, const float* __restrict__ V,
    const float* __restrict__ alpha, const float* __restrict__ vthr,
    float* out, const int* __restrict__ fs) {
  const int b = blockIdx.x;
  if (fs[b] >= TSTEPS - 1) return;
  scan_body(wxbuf, V, alpha, vthr, out, b);
}

// Ungated (tiny-ws tier, round-1 semantics).
__global__ __launch_bounds__(64) void rlif_scan(const float* wxbuf,
                                                const float* __restrict__ V,
                                                const float* __restrict__ alpha,
                                                const float* __restrict__ vthr,
                                                float* out) {
  scan_body(wxbuf, V, alpha, vthr, out, blockIdx.x);
}

// ---------------------------------------------------------------------------
// Tier-B f32 GEMM (round-1-proven).
// ---------------------------------------------------------------------------
__global__ __launch_bounds__(256) void gemm_xwT(const float* __restrict__ x,
                                                const float* __restrict__ W,
                                                float* __restrict__ wx) {
  __shared__ float As[32][64];
  __shared__ float Bs[32][64];
  const int m0 = blockIdx.x * 64;
  const int n0 = blockIdx.y * 64;
  const int tid = threadIdx.x;
  const int tx = tid & 15;
  const int ty = tid >> 4;
  const int lr = tid >> 2;
  const int lk = (tid & 3) * 8;

  float acc[4][4] = {};
  for (int k0 = 0; k0 < KDIM; k0 += 32) {
    const float4* ap =
        reinterpret_cast<const float4*>(x + (size_t)(m0 + lr) * KDIM + k0 + lk);
    const float4* bp =
        reinterpret_cast<const float4*>(W + (size_t)(n0 + lr) * KDIM + k0 + lk);
    float4 a0 = ap[0], a1 = ap[1];
    float4 b0 = bp[0], b1 = bp[1];
    __syncthreads();
    As[lk + 0][lr] = a0.x; As[lk + 1][lr] = a0.y;
    As[lk + 2][lr] = a0.z; As[lk + 3][lr] = a0.w;
    As[lk + 4][lr] = a1.x; As[lk + 5][lr] = a1.y;
    As[lk + 6][lr] = a1.z; As[lk + 7][lr] = a1.w;
    Bs[lk + 0][lr] = b0.x; Bs[lk + 1][lr] = b0.y;
    Bs[lk + 2][lr] = b0.z; Bs[lk + 3][lr] = b0.w;
    Bs[lk + 4][lr] = b1.x; Bs[lk + 5][lr] = b1.y;
    Bs[lk + 6][lr] = b1.z; Bs[lk + 7][lr] = b1.w;
    __syncthreads();
#pragma unroll
    for (int k = 0; k < 32; ++k) {
      float4 av = *reinterpret_cast<const float4*>(&As[k][ty * 4]);
      float4 bv = *reinterpret_cast<const float4*>(&Bs[k][tx * 4]);
      float am[4] = {av.x, av.y, av.z, av.w};
      float bn[4] = {bv.x, bv.y, bv.z, bv.w};
#pragma unroll
      for (int i = 0; i < 4; ++i)
#pragma unroll
        for (int j = 0; j < 4; ++j) acc[i][j] = fmaf(am[i], bn[j], acc[i][j]);
    }
  }
#pragma unroll
  for (int i = 0; i < 4; ++i) {
    float4 o = make_float4(acc[i][0], acc[i][1], acc[i][2], acc[i][3]);
    *reinterpret_cast<float4*>(wx + (size_t)(m0 + ty * 4 + i) * HDIM + n0 +
                               tx * 4) = o;
  }
}

extern "C" void kernel_launch(void* const* d_in, const int* in_sizes, int n_in,
                              void* d_out, int out_size, void* d_ws,
                              size_t ws_size, hipStream_t stream) {
  const float* x = (const float*)d_in[0];      // [32,1000,256]
  const float* W = (const float*)d_in[1];      // [512,256]
  const float* V = (const float*)d_in[2];      // [512,512]
  const float* alpha = (const float*)d_in[3];  // [512]
  const float* vthr = (const float*)d_in[4];   // [512]
  float* out = (float*)d_out;                  // [32,1000,512]

  const size_t wx_b = (size_t)BATCH * TSTEPS * HDIM * 4;  // 65,536,000
  const size_t wh_b = (size_t)HDIM * KDIM * 2;            //    262,144 (each)
  const size_t cb_b = (size_t)NSEG * BATCH * HDIM * 4;    //    524,288
  const size_t needA = wx_b + 2 * wh_b + cb_b + 128;      // ~66.6 MB
  const size_t needB = wx_b + cb_b + 128;

  char* ws = (char*)d_ws;
  if (ws_size >= needA) {
    float* wx = (float*)ws;
    unsigned short* wph = (unsigned short*)(ws + wx_b);
    unsigned short* wpl = wph + (size_t)HDIM * KDIM;
    float* cbuf = (float*)(ws + wx_b + 2 * wh_b);
    int* fs = (int*)(ws + wx_b + 2 * wh_b + cb_b);

    hipLaunchKernelGGL(init_fs, dim3(1), dim3(64), 0, stream, fs);
    hipLaunchKernelGGL(cast_pack, dim3(8), dim3(256), 0, stream, W, wph, wpl,
                       HDIM / 16);
    // 2000 m-tiles, 2 per block (1 per wave) -> 1000 blocks ~ 4 blocks/CU
    hipLaunchKernelGGL(gemm_mfma3, dim3(BATCH * TSTEPS / 32), dim3(128), 0,
                       stream, x, wph, wpl, wx);
    hipLaunchKernelGGL(seg_sum, dim3(BATCH * 7 * 8), dim3(64), 0, stream,
                       wx, alpha, cbuf);
    hipLaunchKernelGGL(seg_scan, dim3(BATCH * NSEG * 8), dim3(64), 0, stream,
                       wx, alpha, vthr, cbuf, out, fs);
    hipLaunchKernelGGL(fallback_scan, dim3(BATCH), dim3(64), 0, stream, wx, V,
                       alpha, vthr, out, fs);
  } else if (ws_size >= needB) {
    float* wx = (float*)ws;
    float* cbuf = (float*)(ws + wx_b);
    int* fs = (int*)(ws + wx_b + cb_b);
    hipLaunchKernelGGL(init_fs, dim3(1), dim3(64), 0, stream, fs);
    hipLaunchKernelGGL(gemm_xwT, dim3(BATCH * TSTEPS / 64, HDIM / 64),
                       dim3(256), 0, stream, x, W, wx);
    hipLaunchKernelGGL(seg_sum, dim3(BATCH * 7 * 8), dim3(64), 0, stream,
                       wx, alpha, cbuf);
    hipLaunchKernelGGL(seg_scan, dim3(BATCH * NSEG * 8), dim3(64), 0, stream,
                       wx, alpha, vthr, cbuf, out, fs);
    hipLaunchKernelGGL(fallback_scan, dim3(BATCH), dim3(64), 0, stream, wx, V,
                       alpha, vthr, out, fs);
  } else {
    float* wx = (ws_size >= wx_b) ? (float*)ws : out;
    hipLaunchKernelGGL(gemm_xwT, dim3(BATCH * TSTEPS / 64, HDIM / 64),
                       dim3(256), 0, stream, x, W, wx);
    hipLaunchKernelGGL(rlif_scan, dim3(BATCH), dim3(64), 0, stream, wx, V,
                       alpha, vthr, out);
  }
}